// Round 7
// baseline (269.427 us; speedup 1.0000x reference)
//
#include <hip/hip_runtime.h>

// Problem: B=32, T=256, D=64
//   out[0, t, b, p, q] = r_p*r_q + i_p*i_q   (real part)
//   out[1, t, b, p, q] = i_p*r_q - r_p*i_q   (imag part)
// where r[p] = real[b, t, p], i[p] = imag[b, t, p].
//
// Pure streaming-store kernel: 268 MB written vs 4 MB read.
// R5 candidate (UNBENCHED — resubmitted verbatim after acquisition timeout):
// native clang vector type for the nontemporal stores
// (__builtin_nontemporal_store rejects HIP_vector_type).
//  - __builtin_nontemporal_store on all output (nt flag: bypass L2/L3
//    write-allocate; 268 MB >> 32 MB L2 so allocate+evict throttled stores)
//  - no LDS / no __syncthreads: j = tid&15 is k-invariant, so each thread
//    needs only one float4 q-segment pair + 4 p-scalars, all from a 512 B
//    L1-hot block-local input region. 8 independent dwordx4 stores per
//    thread issue back-to-back.

namespace {
constexpr int kB = 32;
constexpr int kT = 256;
constexpr int kD = 64;
constexpr int kDD = kD * kD;          // 4096 floats per (t,b) per part

typedef float f32x4 __attribute__((ext_vector_type(4)));
}

__global__ __launch_bounds__(256) void qouter_kernel(
    const float* __restrict__ real,
    const float* __restrict__ imag,
    float* __restrict__ out) {
    const int blk = blockIdx.x;       // 0 .. T*B-1
    const int t = blk / kB;
    const int b = blk % kB;

    const int tid = threadIdx.x;
    // input layout: real[b, t, p] -> real[(b*T + t)*D + p]
    const int in_base = (b * kT + t) * kD;

    const int j  = tid & 15;          // float4 index within q-row (k-invariant)
    const int p0 = tid >> 4;          // base row; rows p0 + 16k, k=0..3

    // One vec4 pair per thread covers this thread's entire q-segment need.
    const f32x4 rq = *reinterpret_cast<const f32x4*>(real + in_base + 4 * j);
    const f32x4 iq = *reinterpret_cast<const f32x4*>(imag + in_base + 4 * j);

    // 4 p-scalars per array (broadcast within each 16-lane group, L1-hot).
    float rp[4], ip[4];
#pragma unroll
    for (int k = 0; k < 4; ++k) {
        rp[k] = real[in_base + p0 + 16 * k];
        ip[k] = imag[in_base + p0 + 16 * k];
    }

    // output layout: out[part, t, b, p, q]
    const size_t base_r = ((size_t)t * kB + b) * kDD;
    const size_t base_i = base_r + (size_t)kT * kB * kDD;
    f32x4* __restrict__ outr = reinterpret_cast<f32x4*>(out + base_r);
    f32x4* __restrict__ outi = reinterpret_cast<f32x4*>(out + base_i);

    // 8 independent nontemporal dwordx4 stores per thread; wave writes
    // 1 KiB contiguous per store instruction (full cache lines).
#pragma unroll
    for (int k = 0; k < 4; ++k) {
        const int idx = tid + k * 256;    // 0..1023; p = p0+16k, q-seg = j
        f32x4 vr, vi;
        vr.x = rp[k] * rq.x + ip[k] * iq.x;
        vr.y = rp[k] * rq.y + ip[k] * iq.y;
        vr.z = rp[k] * rq.z + ip[k] * iq.z;
        vr.w = rp[k] * rq.w + ip[k] * iq.w;
        vi.x = ip[k] * rq.x - rp[k] * iq.x;
        vi.y = ip[k] * rq.y - rp[k] * iq.y;
        vi.z = ip[k] * rq.z - rp[k] * iq.z;
        vi.w = ip[k] * rq.w - rp[k] * iq.w;
        __builtin_nontemporal_store(vr, &outr[idx]);
        __builtin_nontemporal_store(vi, &outi[idx]);
    }
}

extern "C" void kernel_launch(void* const* d_in, const int* in_sizes, int n_in,
                              void* d_out, int out_size, void* d_ws, size_t ws_size,
                              hipStream_t stream) {
    const float* real = (const float*)d_in[0];
    const float* imag = (const float*)d_in[1];
    float* out = (float*)d_out;
    qouter_kernel<<<kT * kB, 256, 0, stream>>>(real, imag, out);
}

// Round 8
// 262.036 us; speedup vs baseline: 1.0282x; 1.0282x over previous
//
#include <hip/hip_runtime.h>

// Problem: B=32, T=256, D=64
//   out[0, t, b, p, q] = r_p*r_q + i_p*i_q   (real part)
//   out[1, t, b, p, q] = i_p*r_q - r_p*i_q   (imag part)
// where r[p] = real[b, t, p], i[p] = imag[b, t, p].
//
// R7 post-mortem: harness fill kernels (1 GiB @ 6.3 TB/s, plain stores) prove
// write-allocate was NOT the throttle; nt stores reverted. Our kernel's
// dispatch is <168 us (absent from top-5), so reported dur includes poison
// fills. Remaining kernel-side theory: store-pipeline shallowness from 8192
// short-lived blocks (8 stores/thread). R8: fill-like structure — 2048 blocks
// x 4 tiles each, long store streams, normal dwordx4 stores, tile i+1 loads
// overlap tile i store drain.

namespace {
constexpr int kB = 32;
constexpr int kT = 256;
constexpr int kD = 64;
constexpr int kDD = kD * kD;          // 4096 floats per (t,b) per part
constexpr int kTilesPerBlock = 4;
constexpr int kBlocks = (kT * kB) / kTilesPerBlock;   // 2048 -> 8 blocks/CU

typedef float f32x4 __attribute__((ext_vector_type(4)));
}

__global__ __launch_bounds__(256) void qouter_kernel(
    const float* __restrict__ real,
    const float* __restrict__ imag,
    float* __restrict__ out) {
    const int tid = threadIdx.x;
    const int j  = tid & 15;          // float4 index within q-row
    const int p0 = tid >> 4;          // base row; rows p0 + 16k, k=0..3

    const int g0 = blockIdx.x * kTilesPerBlock;   // first (t,b) tile
    float* __restrict__ out_i_part = out + (size_t)kT * kB * kDD;

    for (int it = 0; it < kTilesPerBlock; ++it) {
        const int g = g0 + it;        // g = t*32 + b
        const int t = g >> 5;
        const int b = g & 31;
        // input layout: real[b, t, p] -> real[(b*T + t)*D + p]
        const int in_base = (b * kT + t) * kD;

        const f32x4 rq = *reinterpret_cast<const f32x4*>(real + in_base + 4 * j);
        const f32x4 iq = *reinterpret_cast<const f32x4*>(imag + in_base + 4 * j);
        float rp[4], ip[4];
#pragma unroll
        for (int k = 0; k < 4; ++k) {
            rp[k] = real[in_base + p0 + 16 * k];
            ip[k] = imag[in_base + p0 + 16 * k];
        }

        // output layout: out[part, t, b, p, q]; ((t*kB)+b) == g
        f32x4* __restrict__ outr = reinterpret_cast<f32x4*>(out + (size_t)g * kDD);
        f32x4* __restrict__ outi = reinterpret_cast<f32x4*>(out_i_part + (size_t)g * kDD);

#pragma unroll
        for (int k = 0; k < 4; ++k) {
            const int idx = tid + k * 256;    // 0..1023; p = p0+16k, q-seg = j
            f32x4 vr, vi;
            vr.x = rp[k] * rq.x + ip[k] * iq.x;
            vr.y = rp[k] * rq.y + ip[k] * iq.y;
            vr.z = rp[k] * rq.z + ip[k] * iq.z;
            vr.w = rp[k] * rq.w + ip[k] * iq.w;
            vi.x = ip[k] * rq.x - rp[k] * iq.x;
            vi.y = ip[k] * rq.y - rp[k] * iq.y;
            vi.z = ip[k] * rq.z - rp[k] * iq.z;
            vi.w = ip[k] * rq.w - rp[k] * iq.w;
            outr[idx] = vr;
            outi[idx] = vi;
        }
    }
}

extern "C" void kernel_launch(void* const* d_in, const int* in_sizes, int n_in,
                              void* d_out, int out_size, void* d_ws, size_t ws_size,
                              hipStream_t stream) {
    const float* real = (const float*)d_in[0];
    const float* imag = (const float*)d_in[1];
    float* out = (float*)d_out;
    qouter_kernel<<<kBlocks, 256, 0, stream>>>(real, imag, out);
}

// Round 9
// 260.292 us; speedup vs baseline: 1.0351x; 1.0067x over previous
//
#include <hip/hip_runtime.h>

// Problem: B=32, T=256, D=64
//   out[0, t, b, p, q] = r_p*r_q + i_p*i_q   (real part)
//   out[1, t, b, p, q] = i_p*r_q - r_p*i_q   (imag part)
// where r[p] = real[b, t, p], i[p] = imag[b, t, p].
//
// R8 post-mortem: three variants (LDS, nt, 4-tile) all ~262-269 us total.
// Timed region contains a harness 1 GiB poison fill (~164 us @ 6.5 TB/s,
// top-5 of profile); kernel remainder ~98 us = 2.8 TB/s vs fill-proven
// 6.5 TB/s plain-store drain. Remaining structural difference: fill issues
// uninterrupted store streams; we interleave load-groups + vmcnt waits with
// 8-store bursts (~50% store duty cycle).
// R9: prefetch ALL 4 tiles' inputs to registers first (one vmcnt drain),
// then 32 back-to-back dwordx4 stores per thread with no intervening waits.
// Fully unrolled -> static indexing -> registers, no scratch.

namespace {
constexpr int kB = 32;
constexpr int kT = 256;
constexpr int kD = 64;
constexpr int kDD = kD * kD;          // 4096 floats per (t,b) per part
constexpr int kTiles = 4;             // (t,b) tiles per block
constexpr int kBlocks = (kT * kB) / kTiles;   // 2048

typedef float f32x4 __attribute__((ext_vector_type(4)));
}

__global__ __launch_bounds__(256) void qouter_kernel(
    const float* __restrict__ real,
    const float* __restrict__ imag,
    float* __restrict__ out) {
    const int tid = threadIdx.x;
    const int j  = tid & 15;          // float4 index within q-row
    const int p0 = tid >> 4;          // base row; rows p0 + 16k, k=0..3
    const int g0 = blockIdx.x * kTiles;   // first (t,b) tile; g = t*32 + b

    // ---- Phase 1: prefetch all inputs for 4 tiles (40 independent loads,
    // all L1/L2-hot: input is 4 MB total, reused 64x). ----
    f32x4 rq[kTiles], iq[kTiles];
    float rp[kTiles][4], ip[kTiles][4];
#pragma unroll
    for (int it = 0; it < kTiles; ++it) {
        const int g = g0 + it;
        const int t = g >> 5;
        const int b = g & 31;
        // input layout: real[b, t, p] -> real[(b*T + t)*D + p]
        const int in_base = (b * kT + t) * kD;
        rq[it] = *reinterpret_cast<const f32x4*>(real + in_base + 4 * j);
        iq[it] = *reinterpret_cast<const f32x4*>(imag + in_base + 4 * j);
#pragma unroll
        for (int k = 0; k < 4; ++k) {
            rp[it][k] = real[in_base + p0 + 16 * k];
            ip[it][k] = imag[in_base + p0 + 16 * k];
        }
    }

    // ---- Phase 2: 32 back-to-back dwordx4 stores, zero memory waits.
    // Block writes one contiguous 64 KiB span per part (tiles consecutive). ----
    float* __restrict__ out_i_part = out + (size_t)kT * kB * kDD;
#pragma unroll
    for (int it = 0; it < kTiles; ++it) {
        const int g = g0 + it;
        f32x4* __restrict__ outr =
            reinterpret_cast<f32x4*>(out + (size_t)g * kDD);
        f32x4* __restrict__ outi =
            reinterpret_cast<f32x4*>(out_i_part + (size_t)g * kDD);
#pragma unroll
        for (int k = 0; k < 4; ++k) {
            const int idx = tid + k * 256;    // 0..1023; p = p0+16k, q-seg = j
            f32x4 vr, vi;
            vr.x = rp[it][k] * rq[it].x + ip[it][k] * iq[it].x;
            vr.y = rp[it][k] * rq[it].y + ip[it][k] * iq[it].y;
            vr.z = rp[it][k] * rq[it].z + ip[it][k] * iq[it].z;
            vr.w = rp[it][k] * rq[it].w + ip[it][k] * iq[it].w;
            vi.x = ip[it][k] * rq[it].x - rp[it][k] * iq[it].x;
            vi.y = ip[it][k] * rq[it].y - rp[it][k] * iq[it].y;
            vi.z = ip[it][k] * rq[it].z - rp[it][k] * iq[it].z;
            vi.w = ip[it][k] * rq[it].w - rp[it][k] * iq[it].w;
            outr[idx] = vr;
            outi[idx] = vi;
        }
    }
}

extern "C" void kernel_launch(void* const* d_in, const int* in_sizes, int n_in,
                              void* d_out, int out_size, void* d_ws, size_t ws_size,
                              hipStream_t stream) {
    const float* real = (const float*)d_in[0];
    const float* imag = (const float*)d_in[1];
    float* out = (float*)d_out;
    qouter_kernel<<<kBlocks, 256, 0, stream>>>(real, imag, out);
}